// Round 5
// baseline (126.321 us; speedup 1.0000x reference)
//
#include <hip/hip_runtime.h>
#include <hip/hip_bf16.h>

// Shapes
#define BN   64
#define TN   1024
#define EN   512
#define AN   512
#define HN   512
#define G3H  1536

typedef __bf16 bf16x8 __attribute__((ext_vector_type(8)));
typedef __bf16 bf16x4 __attribute__((ext_vector_type(4)));
typedef float  f32x8  __attribute__((ext_vector_type(8)));
typedef float  f32x4  __attribute__((ext_vector_type(4)));
typedef unsigned int uint4v __attribute__((ext_vector_type(4)));

__device__ __forceinline__ float fast_tanh(float x) {
    float e = __expf(2.0f * x);
    return 1.0f - 2.0f / (e + 1.0f);
}
__device__ __forceinline__ float fast_sigmoid(float x) {
    return 1.0f / (1.0f + __expf(-x));
}

// global -> LDS direct copy, 16 bytes per lane (lds dst must be wave-uniform
// base; HW adds lane*16). CK-style addrspace casts.
#define GL2LDS16(gsrc, ldst)                                                  \
    __builtin_amdgcn_global_load_lds(                                         \
        (const __attribute__((address_space(1))) unsigned int*)(gsrc),        \
        (__attribute__((address_space(3))) unsigned int*)(ldst), 16, 0, 0)

// ---------------------------------------------------------------------------
// prep: task-split by blockIdx.x
//   [0,64)      st_proj fp32 GEMV
//   [64,72)     wencT transpose+cvt, PRE-SWIZZLED chunks (XOR within each
//               8-chunk K-window: slot = (C&~7)|((C&7)^(n&7)))
//   [72,840)    wihbf cvt
//   [840,1224)  whhbf cvt
//   [1224,1240) xbf (inputs half)
//   [1240,1256) stbf
//   [1256,1320) zero scores (for score_kernel atomicAdd)
// ---------------------------------------------------------------------------
__global__ __launch_bounds__(256) void prep_kernel(
    const float* __restrict__ states, const float* __restrict__ W_enc,
    const float* __restrict__ W_state, const float* __restrict__ inputs,
    const float* __restrict__ W_ih, const float* __restrict__ W_hh,
    float* __restrict__ stp, __bf16* __restrict__ wencT,
    __bf16* __restrict__ xbf, __bf16* __restrict__ stbf,
    __bf16* __restrict__ wihbf, __bf16* __restrict__ whhbf,
    float* __restrict__ scores)
{
    __shared__ float srow[512];
    int blk = blockIdx.x, tid = threadIdx.x;

    if (blk < 64) {
        int b = blk;
        srow[tid] = states[b * 512 + tid];
        srow[tid + 256] = states[b * 512 + tid + 256];
        __syncthreads();
        int n0 = tid, n1 = tid + 256;
        float a0 = 0.f, a1 = 0.f;
        for (int k = 0; k < 512; ++k) {
            float s = srow[k];
            a0 += s * W_state[k * 512 + n0];
            a1 += s * W_state[k * 512 + n1];
        }
        stp[b * 512 + n0] = a0;
        stp[b * 512 + n1] = a1;
    } else if (blk < 72) {
        int n = (blk - 64) * 64 + (tid & 63);
        int cseg = tid >> 6;
        for (int c = cseg * 16; c < cseg * 16 + 16; ++c) {
            f32x8 f;
            #pragma unroll
            for (int j = 0; j < 8; ++j) f[j] = W_enc[(c * 8 + j) * 512 + n];
            int cs = (c & ~7) | ((c & 7) ^ (n & 7));   // pre-swizzle for score
            *(bf16x8*)(wencT + n * 512 + cs * 8) = __builtin_convertvector(f, bf16x8);
        }
    } else if (blk < 840) {
        int base4 = (blk - 72) * 512 + tid * 2;
        #pragma unroll
        for (int j = 0; j < 2; ++j) {
            int i4 = base4 + j;
            f32x4 f = *(const f32x4*)(W_ih + i4 * 4);
            *(bf16x4*)(wihbf + i4 * 4) = __builtin_convertvector(f, bf16x4);
        }
    } else if (blk < 1224) {
        int base4 = (blk - 840) * 512 + tid * 2;
        #pragma unroll
        for (int j = 0; j < 2; ++j) {
            int i4 = base4 + j;
            f32x4 f = *(const f32x4*)(W_hh + i4 * 4);
            *(bf16x4*)(whhbf + i4 * 4) = __builtin_convertvector(f, bf16x4);
        }
    } else if (blk < 1240) {
        int base4 = (blk - 1224) * 512 + tid * 2;
        #pragma unroll
        for (int j = 0; j < 2; ++j) {
            int i4 = base4 + j;
            int e = i4 * 4;
            int b = e >> 9, c = e & 511;
            f32x4 f = *(const f32x4*)(inputs + e);
            *(bf16x4*)(xbf + b * 1024 + c) = __builtin_convertvector(f, bf16x4);
        }
    } else if (blk < 1256) {
        int base4 = (blk - 1240) * 512 + tid * 2;
        #pragma unroll
        for (int j = 0; j < 2; ++j) {
            int i4 = base4 + j;
            int e = i4 * 4;
            f32x4 f = *(const f32x4*)(states + e);
            *(bf16x4*)(stbf + e) = __builtin_convertvector(f, bf16x4);
        }
    } else {
        int e = (blk - 1256) * 1024 + tid * 4;
        *(f32x4*)(scores + e) = (f32x4){0.f, 0.f, 0.f, 0.f};
    }
}

// ---------------------------------------------------------------------------
// score v4 (m97 regime): 128x128 tile, 256 threads / 4 waves (2x2), wave tile
// 64x64, acc 64 VGPR, BK=64, SINGLE-buffered 33KB LDS -> 3 blocks/CU of
// mutually-async work. B staged via global_load_lds (wencT pre-swizzled in
// prep, LDS linear, fragment read XOR-swizzled). A reg-staged fp32->bf16 with
// XOR-swizzled ds_write + matching read. Chunked XCD swizzle groups the 4
// col-tiles of each A row-panel on one XCD. Fused tanh+v-dot epilogue ->
// atomicAdd into scores.
// ---------------------------------------------------------------------------
__global__ __launch_bounds__(256, 3) void score_kernel(
    const float* __restrict__ enc, const __bf16* __restrict__ wencT,
    const float* __restrict__ stp, const float* __restrict__ v,
    float* __restrict__ scores)
{
    __shared__ __align__(16) __bf16 As[128 * 64];   // 16 KB, swizzled
    __shared__ __align__(16) __bf16 Bs[128 * 64];   // 16 KB, linear (pre-swz src)
    __shared__ float sacc[256];

    int tid = threadIdx.x;
    int bid = blockIdx.x;
    int orig = (bid & 7) * 256 + (bid >> 3);   // bijective chunked XCD swizzle (2048 wgs)
    int rt = orig >> 2, ct = orig & 3;          // consecutive orig = 4 col-tiles of one row-panel
    int grow0 = rt * 128;                       // global row in [0, 65536)
    int c0 = ct * 128;
    int b = grow0 >> 10;

    int lane = tid & 63, wid = tid >> 6;
    int wrow = wid >> 1, wcol = wid & 1;
    int l15 = lane & 15, g = lane >> 4;

    f32x4 acc[4][4];
    #pragma unroll
    for (int m = 0; m < 4; ++m)
        #pragma unroll
        for (int n = 0; n < 4; ++n) acc[m][n] = (f32x4){0.f, 0.f, 0.f, 0.f};

    for (int ks = 0; ks < 8; ++ks) {
        // ---- stage B: 4 x global_load_lds_dwordx4 per thread-slot ----
        #pragma unroll
        for (int i = 0; i < 4; ++i) {
            int p = i * 256 + tid;              // chunk 0..1023 (8B-elem chunks)
            int row = p >> 3, c = p & 7;
            const __bf16* src = wencT + (size_t)(c0 + row) * 512 + ks * 64 + c * 8;
            char* dst = (char*)Bs + (i * 256 + wid * 64) * 16;  // wave-uniform base
            GL2LDS16(src, dst);
        }
        // ---- stage A: fp32 -> bf16, swizzled ds_write ----
        #pragma unroll
        for (int i = 0; i < 4; ++i) {
            int p = i * 256 + tid;
            int row = p >> 3, c = p & 7;
            f32x8 f = *(const f32x8*)(enc + (size_t)(grow0 + row) * 512 + ks * 64 + c * 8);
            int cs = c ^ (row & 7);
            *(bf16x8*)((char*)As + row * 128 + cs * 16) = __builtin_convertvector(f, bf16x8);
        }
        __syncthreads();   // drains vmcnt (gload_lds) + lgkm (ds_write)
        // ---- compute: 32 MFMA ----
        #pragma unroll
        for (int kk = 0; kk < 2; ++kk) {
            bf16x8 af[4], bfr[4];
            #pragma unroll
            for (int m = 0; m < 4; ++m) {
                int row = wrow * 64 + m * 16 + l15;
                int cch = (kk * 4 + g) ^ (row & 7);
                af[m] = *(const bf16x8*)((char*)As + row * 128 + cch * 16);
            }
            #pragma unroll
            for (int n = 0; n < 4; ++n) {
                int row = wcol * 64 + n * 16 + l15;
                int cch = (kk * 4 + g) ^ (row & 7);
                bfr[n] = *(const bf16x8*)((char*)Bs + row * 128 + cch * 16);
            }
            #pragma unroll
            for (int m = 0; m < 4; ++m)
                #pragma unroll
                for (int n = 0; n < 4; ++n)
                    acc[m][n] = __builtin_amdgcn_mfma_f32_16x16x32_bf16(
                        af[m], bfr[n], acc[m][n], 0, 0, 0);
        }
        if (ks < 7) __syncthreads();   // protect As/Bs before next stage
    }

    // fused epilogue: score_row += v[col] * tanh(proj + st_proj[col])
    float sv[4], vw[4];
    #pragma unroll
    for (int n = 0; n < 4; ++n) {
        int col = c0 + wcol * 64 + n * 16 + l15;
        sv[n] = stp[b * 512 + col];
        vw[n] = v[col];
    }
    float rp[16];
    #pragma unroll
    for (int i = 0; i < 16; ++i) rp[i] = 0.f;
    #pragma unroll
    for (int m = 0; m < 4; ++m)
        #pragma unroll
        for (int n = 0; n < 4; ++n) {
            #pragma unroll
            for (int r = 0; r < 4; ++r)
                rp[m * 4 + r] += vw[n] * fast_tanh(acc[m][n][r] + sv[n]);
        }
    #pragma unroll
    for (int i = 0; i < 16; ++i) {
        rp[i] += __shfl_xor(rp[i], 1);
        rp[i] += __shfl_xor(rp[i], 2);
        rp[i] += __shfl_xor(rp[i], 4);
        rp[i] += __shfl_xor(rp[i], 8);
    }
    if (l15 == 0) {
        #pragma unroll
        for (int m = 0; m < 4; ++m)
            #pragma unroll
            for (int r = 0; r < 4; ++r)
                sacc[wcol * 128 + wrow * 64 + m * 16 + g * 4 + r] = rp[m * 4 + r];
    }
    __syncthreads();
    if (tid < 128)
        atomicAdd(scores + grow0 + tid, sacc[tid] + sacc[128 + tid]);
}

// ---------------------------------------------------------------------------
// ctx (unchanged): softmax + context, writes bf16 context half of x.
// ---------------------------------------------------------------------------
__global__ __launch_bounds__(256) void ctx_kernel(
    const float* __restrict__ scores, const float* __restrict__ enc,
    __bf16* __restrict__ xbf)
{
    __shared__ float wsm[1024];
    __shared__ float red[512];
    __shared__ float tmp[8];
    int tid = threadIdx.x, lane = tid & 63, w = tid >> 6;
    int b = blockIdx.x >> 2, c0 = (blockIdx.x & 3) * 128;

    f32x4 s = *(const f32x4*)(scores + b * 1024 + tid * 4);
    float m = fmaxf(fmaxf(s[0], s[1]), fmaxf(s[2], s[3]));
    #pragma unroll
    for (int off = 32; off >= 1; off >>= 1) m = fmaxf(m, __shfl_xor(m, off));
    if (lane == 0) tmp[w] = m;
    __syncthreads();
    float M = fmaxf(fmaxf(tmp[0], tmp[1]), fmaxf(tmp[2], tmp[3]));
    float e0 = __expf(s[0] - M), e1 = __expf(s[1] - M);
    float e2 = __expf(s[2] - M), e3 = __expf(s[3] - M);
    wsm[tid * 4 + 0] = e0; wsm[tid * 4 + 1] = e1;
    wsm[tid * 4 + 2] = e2; wsm[tid * 4 + 3] = e3;
    float sum = e0 + e1 + e2 + e3;
    #pragma unroll
    for (int off = 32; off >= 1; off >>= 1) sum += __shfl_xor(sum, off);
    if (lane == 0) tmp[4 + w] = sum;
    __syncthreads();
    float S = tmp[4] + tmp[5] + tmp[6] + tmp[7];

    const float* ep = enc + ((b * 1024 + w * 256) * 512 + c0 + lane * 2);
    float ax = 0.f, ay = 0.f;
    #pragma unroll 4
    for (int t = 0; t < 256; ++t) {
        float wt = wsm[w * 256 + t];
        float2 ev = *(const float2*)(ep + t * 512);
        ax += wt * ev.x;
        ay += wt * ev.y;
    }
    red[w * 128 + lane * 2] = ax;
    red[w * 128 + lane * 2 + 1] = ay;
    __syncthreads();
    if (tid < 128) {
        float c = (red[tid] + red[128 + tid] + red[256 + tid] + red[384 + tid]) / S;
        xbf[b * 1024 + 512 + c0 + tid] = (__bf16)c;
    }
}

// ---------------------------------------------------------------------------
// gru_gemm (unchanged)
// ---------------------------------------------------------------------------
__global__ __launch_bounds__(256) void gru_gemm(
    const __bf16* __restrict__ xbf, const __bf16* __restrict__ stbf,
    const __bf16* __restrict__ wihbf, const __bf16* __restrict__ whhbf,
    const float* __restrict__ b_ih, const float* __restrict__ b_hh,
    float* __restrict__ gi, float* __restrict__ gh)
{
    __shared__ __align__(16) __bf16 As[64 * 72];
    __shared__ __align__(16) __bf16 Bs[128 * 72];
    int blk = blockIdx.x, tid = threadIdx.x;
    bool is_gh = blk >= 12;
    int n0 = (is_gh ? blk - 12 : blk) * 128;
    int K = is_gh ? 512 : 1024;
    const __bf16* Aptr = is_gh ? stbf : xbf;
    const __bf16* Bptr = is_gh ? whhbf : wihbf;
    const float* bias = is_gh ? b_hh : b_ih;
    float* outp = is_gh ? gh : gi;

    int lane = tid & 63, wid = tid >> 6, l15 = lane & 15, g = lane >> 4;
    f32x4 acc[4][2];
    #pragma unroll
    for (int i = 0; i < 4; ++i)
        #pragma unroll
        for (int j = 0; j < 2; ++j) acc[i][j] = (f32x4){0.f, 0.f, 0.f, 0.f};

    int nkc = K >> 6;
    for (int kc = 0; kc < nkc; ++kc) {
        int k0 = kc * 64;
        #pragma unroll
        for (int q = 0; q < 2; ++q) {
            int ch = tid * 2 + q, row = ch >> 3, seg = ch & 7;
            uint4v u = *(const uint4v*)(Aptr + row * K + k0 + seg * 8);
            *(uint4v*)(As + row * 72 + seg * 8) = u;
        }
        #pragma unroll
        for (int q = 0; q < 4; ++q) {
            int ch = tid * 4 + q, row = ch >> 3, seg = ch & 7;
            uint4v u = *(const uint4v*)(Bptr + (n0 + row) * K + k0 + seg * 8);
            *(uint4v*)(Bs + row * 72 + seg * 8) = u;
        }
        __syncthreads();
        #pragma unroll
        for (int kk = 0; kk < 2; ++kk) {
            bf16x8 af[4], bfr[2];
            #pragma unroll
            for (int m = 0; m < 4; ++m)
                af[m] = *(const bf16x8*)(As + (m * 16 + l15) * 72 + kk * 32 + g * 8);
            #pragma unroll
            for (int n = 0; n < 2; ++n)
                bfr[n] = *(const bf16x8*)(Bs + (wid * 32 + n * 16 + l15) * 72 + kk * 32 + g * 8);
            #pragma unroll
            for (int m = 0; m < 4; ++m)
                #pragma unroll
                for (int n = 0; n < 2; ++n)
                    acc[m][n] = __builtin_amdgcn_mfma_f32_16x16x32_bf16(
                        af[m], bfr[n], acc[m][n], 0, 0, 0);
        }
        __syncthreads();
    }
    #pragma unroll
    for (int m = 0; m < 4; ++m)
        #pragma unroll
        for (int n = 0; n < 2; ++n) {
            int col = n0 + wid * 32 + n * 16 + l15;
            float bb = bias[col];
            #pragma unroll
            for (int r = 0; r < 4; ++r) {
                int brow = m * 16 + g * 4 + r;
                outp[brow * 1536 + col] = acc[m][n][r] + bb;
            }
        }
}

// ---------------------------------------------------------------------------
// gates (unchanged)
// ---------------------------------------------------------------------------
__global__ __launch_bounds__(256) void gru_gates(
    const float* __restrict__ gi, const float* __restrict__ gh,
    const float* __restrict__ states, float* __restrict__ out)
{
    int i = blockIdx.x * 256 + threadIdx.x;  // 32768 total
    int b = i >> 9, j = i & 511;
    const float* gib = gi + b * 1536;
    const float* ghb = gh + b * 1536;
    float r = fast_sigmoid(gib[j] + ghb[j]);
    float z = fast_sigmoid(gib[512 + j] + ghb[512 + j]);
    float n = fast_tanh(gib[1024 + j] + r * ghb[1024 + j]);
    out[i] = (1.f - z) * n + z * states[i];
}

// ---------------------------------------------------------------------------
extern "C" void kernel_launch(void* const* d_in, const int* in_sizes, int n_in,
                              void* d_out, int out_size, void* d_ws, size_t ws_size,
                              hipStream_t stream)
{
    const float* inputs  = (const float*)d_in[0];
    const float* states  = (const float*)d_in[1];
    const float* encoded = (const float*)d_in[2];
    const float* W_enc   = (const float*)d_in[3];
    const float* W_state = (const float*)d_in[4];
    const float* v       = (const float*)d_in[5];
    const float* W_ih    = (const float*)d_in[6];
    const float* W_hh    = (const float*)d_in[7];
    const float* b_ih    = (const float*)d_in[8];
    const float* b_hh    = (const float*)d_in[9];
    float* out = (float*)d_out;
    char* ws = (char*)d_ws;

    float*  stp    = (float*)(ws + 0);         //  64*512*4   = 131072
    __bf16* wencT  = (__bf16*)(ws + 131072);   // 512*512*2   = 524288
    float*  scores = (float*)(ws + 655360);    //  64*1024*4  = 262144
    __bf16* xbf    = (__bf16*)(ws + 917504);   //  64*1024*2  = 131072
    __bf16* stbf   = (__bf16*)(ws + 1048576);  //  64*512*2   = 65536
    __bf16* wihbf  = (__bf16*)(ws + 1114112);  // 1536*1024*2 = 3145728
    __bf16* whhbf  = (__bf16*)(ws + 4259840);  // 1536*512*2  = 1572864
    float*  gi     = (float*)(ws + 5832704);   //  64*1536*4  = 393216
    float*  gh     = (float*)(ws + 6225920);   //  64*1536*4  = 393216

    prep_kernel<<<1320, 256, 0, stream>>>(states, W_enc, W_state, inputs, W_ih, W_hh,
                                          stp, wencT, xbf, stbf, wihbf, whhbf, scores);
    score_kernel<<<2048, 256, 0, stream>>>(encoded, wencT, stp, v, scores);
    ctx_kernel<<<256, 256, 0, stream>>>(scores, encoded, xbf);
    gru_gemm<<<24, 256, 0, stream>>>(xbf, stbf, wihbf, whhbf, b_ih, b_hh, gi, gh);
    gru_gates<<<128, 256, 0, stream>>>(gi, gh, states, out);
}